// Round 4
// baseline (516.798 us; speedup 1.0000x reference)
//
#include <hip/hip_runtime.h>
#include <cstdint>

#define NH 16
#define DH 64
#define FF 4096
#define PP 512
#define BB 2048

typedef __bf16 bf16x8 __attribute__((ext_vector_type(8)));
typedef float f32x4 __attribute__((ext_vector_type(4)));
typedef float fl4 __attribute__((ext_vector_type(4)));
typedef unsigned short us4 __attribute__((ext_vector_type(4)));
typedef unsigned int u32x2 __attribute__((ext_vector_type(2)));

__device__ __forceinline__ unsigned short f2bf(float f) {
  unsigned u = __float_as_uint(f);
  u += 0x7FFFu + ((u >> 16) & 1u);
  return (unsigned short)(u >> 16);
}

// pack two f32 -> two bf16 (round-half-up: +0x8000, take high16s via v_perm)
__device__ __forceinline__ unsigned int pkbf(float lo, float hi) {
  unsigned a = __float_as_uint(lo) + 0x8000u;
  unsigned b = __float_as_uint(hi) + 0x8000u;
  return __builtin_amdgcn_perm(b, a, 0x07060302u);
}

// async global->LDS, 16B/lane. LDS dest = wave-uniform base + lane*16;
// global source is per-lane arbitrary (exploited for the XOR swizzle).
__device__ __forceinline__ void gload_lds16(const void* g, void* l) {
  __builtin_amdgcn_global_load_lds(
      (const __attribute__((address_space(1))) void*)g,
      (__attribute__((address_space(3))) void*)(unsigned int)(unsigned long long)l,
      16, 0, 0);
}

// one kernel converts all three fp32 inputs to bf16 (saves 2 launches)
__global__ void cvt_all(const float* __restrict__ x, const float* __restrict__ f,
                        const float* __restrict__ p,
                        unsigned short* __restrict__ xb,
                        unsigned short* __restrict__ fb,
                        unsigned short* __restrict__ pb) {
  const int nx = BB * 1024 / 4, nf = FF * 1024 / 4, np = PP * 1024 / 4;
  int i = blockIdx.x * blockDim.x + threadIdx.x;
  const fl4* src;
  us4* dst;
  if (i < nx) {
    src = (const fl4*)x + i;
    dst = (us4*)xb + i;
  } else if (i < nx + nf) {
    src = (const fl4*)f + (i - nx);
    dst = (us4*)fb + (i - nx);
  } else if (i < nx + nf + np) {
    src = (const fl4*)p + (i - nx - nf);
    dst = (us4*)pb + (i - nx - nf);
  } else {
    return;
  }
  fl4 v = *src;
  us4 o;
  o.x = f2bf(v.x); o.y = f2bf(v.y); o.z = f2bf(v.z); o.w = f2bf(v.w);
  *dst = o;
}

// ---------------------------------------------------------------------------
// Phase 1: per-head [P x F, K=64] GEMM on prototypes.
//   Q1 = th*Pw + al*Pp - al,  Q2 = be*Pw   (layout [h][p][f], bf16)
//   pws[h][p] += be * sum_f Pw
// ---------------------------------------------------------------------------
__global__ __launch_bounds__(256, 2) void gemm_proto(
    const unsigned short* __restrict__ Abf, const unsigned short* __restrict__ Fbf,
    unsigned short* __restrict__ O1, unsigned short* __restrict__ O2,
    float* __restrict__ pws,
    const float* __restrict__ theta, const float* __restrict__ alpha,
    const float* __restrict__ beta) {
  const int h = blockIdx.z;
  const int n0 = blockIdx.x * 128;   // f tile
  const int lm0 = blockIdx.y * 128;  // p tile
  const int t = threadIdx.x;

  __shared__ __align__(16) char As[128 * 128];
  __shared__ __align__(16) char Bs[128 * 128];

  {
    const char* ab = (const char*)(Abf + (size_t)lm0 * 1024 + h * 64);
    const char* bb = (const char*)(Fbf + (size_t)n0 * 1024 + h * 64);
#pragma unroll
    for (int r = 0; r < 4; ++r) {
      int o = r * 4096 + t * 16;
      int row = o >> 7, col = o & 127;
      gload_lds16(ab + (size_t)row * 2048 + col, As + o);
      gload_lds16(bb + (size_t)row * 2048 + col, Bs + o);
    }
  }
  __syncthreads();

  const int wave = t >> 6, lane = t & 63;
  const int wm = wave & 1, wn = wave >> 1;
  const int quad = lane >> 4, lr = lane & 15;

  f32x4 acc[4][4];
#pragma unroll
  for (int i = 0; i < 4; ++i)
#pragma unroll
    for (int j = 0; j < 4; ++j) acc[i][j] = (f32x4){0.f, 0.f, 0.f, 0.f};

#pragma unroll
  for (int s = 0; s < 2; ++s) {
    bf16x8 av[4], bv[4];
#pragma unroll
    for (int fm = 0; fm < 4; ++fm) {
      int row = wm * 64 + fm * 16 + lr;
      av[fm] = *(const bf16x8*)(As + row * 128 + s * 64 + quad * 16);
    }
#pragma unroll
    for (int fn = 0; fn < 4; ++fn) {
      int row = wn * 64 + fn * 16 + lr;
      bv[fn] = *(const bf16x8*)(Bs + row * 128 + s * 64 + quad * 16);
    }
#pragma unroll
    for (int fm = 0; fm < 4; ++fm)
#pragma unroll
      for (int fn = 0; fn < 4; ++fn)
        acc[fm][fn] = __builtin_amdgcn_mfma_f32_16x16x32_bf16(av[fm], bv[fn],
                                                              acc[fm][fn], 0, 0, 0);
  }

  const float th = theta[h], al = alpha[h], be = beta[h];

#pragma unroll
  for (int fm = 0; fm < 4; ++fm) {
    int prow = lm0 + wm * 64 + fm * 16 + quad * 4;
    float rs0 = 0.f, rs1 = 0.f, rs2 = 0.f, rs3 = 0.f;
#pragma unroll
    for (int fn = 0; fn < 4; ++fn) {
      int f = n0 + wn * 64 + fn * 16 + lr;
#pragma unroll
      for (int i = 0; i < 4; ++i) {
        float pf = acc[fm][fn][i];
        float pp = fmaxf(pf, 0.f);
        float pw = pf * pp;
        size_t idx = ((size_t)(h * PP + prow + i)) * FF + f;
        O1[idx] = f2bf(th * pw + al * pp - al);
        O2[idx] = f2bf(be * pw);
        if (i == 0) rs0 += pw;
        else if (i == 1) rs1 += pw;
        else if (i == 2) rs2 += pw;
        else rs3 += pw;
      }
    }
    float rs[4] = {rs0, rs1, rs2, rs3};
#pragma unroll
    for (int i = 0; i < 4; ++i) {
      float s = rs[i];
      s += __shfl_xor(s, 1);
      s += __shfl_xor(s, 2);
      s += __shfl_xor(s, 4);
      s += __shfl_xor(s, 8);
      if (lr == 0) atomicAdd(&pws[h * PP + prow + i], be * s);
    }
  }
}

// ---------------------------------------------------------------------------
// Fused main: per (p-tile 256, b-tile 64, head) block, single pass over F
// in steps of KT=32. Per f-step:
//   A: stage Fh(32x64), Q1(256x32), Q2(256x32) via swizzled global_load_lds.
//   B: Xf[f][b] = Fh . Xh^T via MFMA (Xh in registers; wave owns 16 b rows).
//   C: Xw = xf*relu(xf), Xp = relu(xf) -> packed 8B LDS writes (swizzled).
//   D: acc += Xw.Q1^T + Xp.Q2^T  (waves split the 256 p cols, 4 each of 64).
// Recompute overhead = 64/(2*256) = 12.5% of MFMA.
// LDS = 4+16+16+4+4 = 44 KB -> 3 blocks/CU (12 waves/CU) for latency hiding.
// Grid 2x32x16 = 1024 blocks.
// ---------------------------------------------------------------------------
__global__ __launch_bounds__(256, 3) void fused_main(
    const unsigned short* __restrict__ x_bf, const unsigned short* __restrict__ f_bf,
    const unsigned short* __restrict__ Q1, const unsigned short* __restrict__ Q2,
    const float* __restrict__ pws, float* __restrict__ out) {
  const int h = blockIdx.z;
  const int n0 = blockIdx.x * 256;  // p tile
  const int m0 = blockIdx.y * 64;   // b tile
  const int t = threadIdx.x;
  const int wave = t >> 6, lane = t & 63;
  const int quad = lane >> 4, lr = lane & 15;
  const int key8 = lr & 7;         // swizzle key, 128B-row buffer (sF)
  const int key2 = (lr >> 1) & 3;  // swizzle key, 64B-row buffers (sQ/sX)

  __shared__ __align__(16) char sF[4096];
  __shared__ __align__(16) char sQ1[16384];
  __shared__ __align__(16) char sQ2[16384];
  __shared__ __align__(16) char sXw[4096];
  __shared__ __align__(16) char sXp[4096];

  // Xh B-operand fragments: wave owns b = m0 + wave*16 + lr
  bf16x8 xh[2];  // [s]: k = s*32 + quad*8 + j over d=64
#pragma unroll
  for (int s = 0; s < 2; ++s) {
    int b = m0 + wave * 16 + lr;
    xh[s] = *(const bf16x8*)(x_bf + (size_t)b * 1024 + h * 64 + s * 32 + quad * 8);
  }

  // ---- hoisted LDS byte offsets ----
  int af_off[2][2];  // step B: sF row fm*16+lr, chunk s*4+quad
#pragma unroll
  for (int fm = 0; fm < 2; ++fm)
#pragma unroll
    for (int s = 0; s < 2; ++s)
      af_off[fm][s] = (fm * 16 + lr) * 128 + (((s * 4 + quad) ^ key8) * 16);

  int cw_off[2];  // step C: row wave*16+lr, logical chunk fm*2+(quad>>1)
#pragma unroll
  for (int fm = 0; fm < 2; ++fm)
    cw_off[fm] = (wave * 16 + lr) * 64 +
                 (((fm * 2 + (quad >> 1)) ^ key2) * 16) + (quad & 1) * 8;

  int aw_off[4];  // step D A reads: row fm*16+lr, chunk quad
#pragma unroll
  for (int fm = 0; fm < 4; ++fm)
    aw_off[fm] = (fm * 16 + lr) * 64 + ((quad ^ key2) * 16);

  int bq_off[4];  // step D B reads: row wave*64+fn*16+lr, chunk quad
#pragma unroll
  for (int fn = 0; fn < 4; ++fn)
    bq_off[fn] = (wave * 64 + fn * 16 + lr) * 64 + ((quad ^ key2) * 16);

  // ---- staging source pointers (swizzle applied on the GLOBAL side) ----
  const char* srcF;
  {
    int row = t >> 3, c = t & 7, cs = c ^ (row & 7);
    srcF = (const char*)f_bf + h * 128 + (size_t)row * 2048 + cs * 16;
  }
  const char* srcQ1[4];
  const char* srcQ2[4];
  {
    const char* q1b = (const char*)(Q1 + ((size_t)h * PP + n0) * FF);
    const char* q2b = (const char*)(Q2 + ((size_t)h * PP + n0) * FF);
#pragma unroll
    for (int r = 0; r < 4; ++r) {
      int ci = r * 256 + t, row = ci >> 2, c = ci & 3, cs = c ^ ((row >> 1) & 3);
      srcQ1[r] = q1b + (size_t)row * 8192 + cs * 16;
      srcQ2[r] = q2b + (size_t)row * 8192 + cs * 16;
    }
  }

  f32x4 acc[4][4];
#pragma unroll
  for (int i = 0; i < 4; ++i)
#pragma unroll
    for (int j = 0; j < 4; ++j) acc[i][j] = (f32x4){0.f, 0.f, 0.f, 0.f};

  for (int it = 0; it < FF / 32; ++it) {
    __syncthreads();  // previous iteration's LDS reads complete
    gload_lds16(srcF, sF + t * 16);
    srcF += 32 * 2048;
#pragma unroll
    for (int r = 0; r < 4; ++r) {
      gload_lds16(srcQ1[r], sQ1 + r * 4096 + t * 16);
      gload_lds16(srcQ2[r], sQ2 + r * 4096 + t * 16);
      srcQ1[r] += 64;
      srcQ2[r] += 64;
    }
    __syncthreads();  // staging visible

    // step B: Xf[f 0..31][b = wave's 16 rows]
    f32x4 xf[2];
    xf[0] = (f32x4){0.f, 0.f, 0.f, 0.f};
    xf[1] = (f32x4){0.f, 0.f, 0.f, 0.f};
#pragma unroll
    for (int s = 0; s < 2; ++s)
#pragma unroll
      for (int fm = 0; fm < 2; ++fm) {
        bf16x8 af = *(const bf16x8*)(sF + af_off[fm][s]);
        xf[fm] = __builtin_amdgcn_mfma_f32_16x16x32_bf16(af, xh[s], xf[fm], 0, 0, 0);
      }

    // step C: transform + pack (lane holds f = fm*16+quad*4+i, b = wave*16+lr)
#pragma unroll
    for (int fm = 0; fm < 2; ++fm) {
      float v0 = xf[fm][0], v1 = xf[fm][1], v2 = xf[fm][2], v3 = xf[fm][3];
      float p0 = fmaxf(v0, 0.f), p1 = fmaxf(v1, 0.f);
      float p2 = fmaxf(v2, 0.f), p3 = fmaxf(v3, 0.f);
      u32x2 w, p;
      w.x = pkbf(v0 * p0, v1 * p1);
      w.y = pkbf(v2 * p2, v3 * p3);
      p.x = pkbf(p0, p1);
      p.y = pkbf(p2, p3);
      *(u32x2*)(sXw + cw_off[fm]) = w;
      *(u32x2*)(sXp + cw_off[fm]) = p;
    }
    __syncthreads();  // Xw/Xp visible

    // step D: acc += Xw.Q1^T + Xp.Q2^T  (K=32)
    bf16x8 aw[4], ap[4];
#pragma unroll
    for (int fm = 0; fm < 4; ++fm) {
      aw[fm] = *(const bf16x8*)(sXw + aw_off[fm]);
      ap[fm] = *(const bf16x8*)(sXp + aw_off[fm]);
    }
#pragma unroll
    for (int fn = 0; fn < 4; ++fn) {
      bf16x8 b1 = *(const bf16x8*)(sQ1 + bq_off[fn]);
      bf16x8 b2 = *(const bf16x8*)(sQ2 + bq_off[fn]);
#pragma unroll
      for (int fm = 0; fm < 4; ++fm) {
        acc[fm][fn] = __builtin_amdgcn_mfma_f32_16x16x32_bf16(aw[fm], b1,
                                                              acc[fm][fn], 0, 0, 0);
        acc[fm][fn] = __builtin_amdgcn_mfma_f32_16x16x32_bf16(ap[fm], b2,
                                                              acc[fm][fn], 0, 0, 0);
      }
    }
  }

  // epilogue: subtract pws, store fp32
#pragma unroll
  for (int fn = 0; fn < 4; ++fn) {
    int p = n0 + wave * 64 + fn * 16 + lr;
    float sub = pws[h * PP + p];
#pragma unroll
    for (int fm = 0; fm < 4; ++fm) {
      int brow = m0 + fm * 16 + quad * 4;
#pragma unroll
      for (int i = 0; i < 4; ++i) {
        out[(size_t)(brow + i) * (NH * PP) + h * PP + p] = acc[fm][fn][i] - sub;
      }
    }
  }
}

extern "C" void kernel_launch(void* const* d_in, const int* in_sizes, int n_in,
                              void* d_out, int out_size, void* d_ws, size_t ws_size,
                              hipStream_t stream) {
  const float* x = (const float*)d_in[0];
  const float* features = (const float*)d_in[1];
  const float* prototypes = (const float*)d_in[2];
  const float* theta = (const float*)d_in[3];
  const float* alpha = (const float*)d_in[4];
  const float* beta = (const float*)d_in[5];
  float* out = (float*)d_out;

  char* ws = (char*)d_ws;
  size_t off = 0;
  auto carve = [&](size_t bytes) -> char* {
    char* p = ws + off;
    off += (bytes + 255) & ~(size_t)255;
    return p;
  };
  unsigned short* x_bf = (unsigned short*)carve((size_t)BB * 1024 * 2);
  unsigned short* f_bf = (unsigned short*)carve((size_t)FF * 1024 * 2);
  unsigned short* p_bf = (unsigned short*)carve((size_t)PP * 1024 * 2);
  unsigned short* Q1 = (unsigned short*)carve((size_t)NH * PP * FF * 2);
  unsigned short* Q2 = (unsigned short*)carve((size_t)NH * PP * FF * 2);
  float* pws = (float*)carve((size_t)NH * PP * 4);

  const int ncvt = (BB + FF + PP) * 1024 / 4;
  cvt_all<<<(ncvt + 255) / 256, 256, 0, stream>>>(x, features, prototypes,
                                                  x_bf, f_bf, p_bf);
  hipMemsetAsync(pws, 0, (size_t)NH * PP * 4, stream);

  // Phase 1: prototypes -> Q1, Q2, pws
  gemm_proto<<<dim3(FF / 128, PP / 128, NH), 256, 0, stream>>>(
      p_bf, f_bf, Q1, Q2, pws, theta, alpha, beta);

  // Fused main GEMM
  fused_main<<<dim3(PP / 256, BB / 64, NH), 256, 0, stream>>>(
      x_bf, f_bf, Q1, Q2, pws, out);
}

// Round 5
// 407.934 us; speedup vs baseline: 1.2669x; 1.2669x over previous
//
#include <hip/hip_runtime.h>
#include <cstdint>

#define NH 16
#define DH 64
#define FF 4096
#define PP 512
#define BB 2048

typedef __bf16 bf16x8 __attribute__((ext_vector_type(8)));
typedef float f32x4 __attribute__((ext_vector_type(4)));
typedef float fl4 __attribute__((ext_vector_type(4)));
typedef unsigned short us4 __attribute__((ext_vector_type(4)));
typedef unsigned int u32x2 __attribute__((ext_vector_type(2)));

__device__ __forceinline__ unsigned short f2bf(float f) {
  unsigned u = __float_as_uint(f);
  u += 0x7FFFu + ((u >> 16) & 1u);
  return (unsigned short)(u >> 16);
}

// pack two f32 -> two bf16 (round-half-up: +0x8000, take high16s via v_perm)
__device__ __forceinline__ unsigned int pkbf(float lo, float hi) {
  unsigned a = __float_as_uint(lo) + 0x8000u;
  unsigned b = __float_as_uint(hi) + 0x8000u;
  return __builtin_amdgcn_perm(b, a, 0x07060302u);
}

// async global->LDS, 16B/lane. LDS dest = wave-uniform base + lane*16;
// global source is per-lane arbitrary (exploited for the XOR swizzle).
__device__ __forceinline__ void gload_lds16(const void* g, void* l) {
  __builtin_amdgcn_global_load_lds(
      (const __attribute__((address_space(1))) void*)g,
      (__attribute__((address_space(3))) void*)(unsigned int)(unsigned long long)l,
      16, 0, 0);
}

// convert features + prototypes fp32 -> bf16 (x is consumed fp32 directly)
__global__ void cvt_fp(const float* __restrict__ f, const float* __restrict__ p,
                       unsigned short* __restrict__ fb,
                       unsigned short* __restrict__ pb) {
  const int nf = FF * 1024 / 4, np = PP * 1024 / 4;
  int i = blockIdx.x * blockDim.x + threadIdx.x;
  const fl4* src;
  us4* dst;
  if (i < nf) {
    src = (const fl4*)f + i;
    dst = (us4*)fb + i;
  } else if (i < nf + np) {
    src = (const fl4*)p + (i - nf);
    dst = (us4*)pb + (i - nf);
  } else {
    return;
  }
  fl4 v = *src;
  us4 o;
  o.x = f2bf(v.x); o.y = f2bf(v.y); o.z = f2bf(v.z); o.w = f2bf(v.w);
  *dst = o;
}

// ---------------------------------------------------------------------------
// Phase 1: per-head [P x F, K=64] GEMM on prototypes.
//   Q1 = th*Pw + al*Pp - al,  Q2 = be*Pw   (layout [h][p][f], bf16)
//   pws[h][p] += be * sum_f Pw
// ---------------------------------------------------------------------------
__global__ __launch_bounds__(256, 2) void gemm_proto(
    const unsigned short* __restrict__ Abf, const unsigned short* __restrict__ Fbf,
    unsigned short* __restrict__ O1, unsigned short* __restrict__ O2,
    float* __restrict__ pws,
    const float* __restrict__ theta, const float* __restrict__ alpha,
    const float* __restrict__ beta) {
  const int h = blockIdx.z;
  const int n0 = blockIdx.x * 128;   // f tile
  const int lm0 = blockIdx.y * 128;  // p tile
  const int t = threadIdx.x;

  __shared__ __align__(16) char As[128 * 128];
  __shared__ __align__(16) char Bs[128 * 128];

  {
    const char* ab = (const char*)(Abf + (size_t)lm0 * 1024 + h * 64);
    const char* bb = (const char*)(Fbf + (size_t)n0 * 1024 + h * 64);
#pragma unroll
    for (int r = 0; r < 4; ++r) {
      int o = r * 4096 + t * 16;
      int row = o >> 7, col = o & 127;
      gload_lds16(ab + (size_t)row * 2048 + col, As + o);
      gload_lds16(bb + (size_t)row * 2048 + col, Bs + o);
    }
  }
  __syncthreads();

  const int wave = t >> 6, lane = t & 63;
  const int wm = wave & 1, wn = wave >> 1;
  const int quad = lane >> 4, lr = lane & 15;

  f32x4 acc[4][4];
#pragma unroll
  for (int i = 0; i < 4; ++i)
#pragma unroll
    for (int j = 0; j < 4; ++j) acc[i][j] = (f32x4){0.f, 0.f, 0.f, 0.f};

#pragma unroll
  for (int s = 0; s < 2; ++s) {
    bf16x8 av[4], bv[4];
#pragma unroll
    for (int fm = 0; fm < 4; ++fm) {
      int row = wm * 64 + fm * 16 + lr;
      av[fm] = *(const bf16x8*)(As + row * 128 + s * 64 + quad * 16);
    }
#pragma unroll
    for (int fn = 0; fn < 4; ++fn) {
      int row = wn * 64 + fn * 16 + lr;
      bv[fn] = *(const bf16x8*)(Bs + row * 128 + s * 64 + quad * 16);
    }
#pragma unroll
    for (int fm = 0; fm < 4; ++fm)
#pragma unroll
      for (int fn = 0; fn < 4; ++fn)
        acc[fm][fn] = __builtin_amdgcn_mfma_f32_16x16x32_bf16(av[fm], bv[fn],
                                                              acc[fm][fn], 0, 0, 0);
  }

  const float th = theta[h], al = alpha[h], be = beta[h];

#pragma unroll
  for (int fm = 0; fm < 4; ++fm) {
    int prow = lm0 + wm * 64 + fm * 16 + quad * 4;
    float rs0 = 0.f, rs1 = 0.f, rs2 = 0.f, rs3 = 0.f;
#pragma unroll
    for (int fn = 0; fn < 4; ++fn) {
      int f = n0 + wn * 64 + fn * 16 + lr;
#pragma unroll
      for (int i = 0; i < 4; ++i) {
        float pf = acc[fm][fn][i];
        float pp = fmaxf(pf, 0.f);
        float pw = pf * pp;
        size_t idx = ((size_t)(h * PP + prow + i)) * FF + f;
        O1[idx] = f2bf(th * pw + al * pp - al);
        O2[idx] = f2bf(be * pw);
        if (i == 0) rs0 += pw;
        else if (i == 1) rs1 += pw;
        else if (i == 2) rs2 += pw;
        else rs3 += pw;
      }
    }
    float rs[4] = {rs0, rs1, rs2, rs3};
#pragma unroll
    for (int i = 0; i < 4; ++i) {
      float s = rs[i];
      s += __shfl_xor(s, 1);
      s += __shfl_xor(s, 2);
      s += __shfl_xor(s, 4);
      s += __shfl_xor(s, 8);
      if (lr == 0) atomicAdd(&pws[h * PP + prow + i], be * s);
    }
  }
}

// ---------------------------------------------------------------------------
// Fused main (round-3 winner config): per (p-tile 256, b-tile 128, head)
// block, single pass over F in steps of KT=32. Per f-step:
//   A: stage Fh(32x64), Q1(256x32), Q2(256x32) via swizzled global_load_lds.
//   B: Xf[f][b] = Fh . Xh^T via MFMA (Xh fragments in registers).
//   C: Xw = xf*relu(xf), Xp = relu(xf) -> packed 8B LDS writes (swizzled).
//   D: acc += Xw.Q1^T + Xp.Q2^T  (one accumulator, 64 MFMA/wave).
// Recompute = 12.5% of MFMA. Staging 36KB per 288 block-MFMA keeps the LDS
// DMA below MFMA issue time (b=64 variant broke this -- round-4 lesson).
// LDS = 4+16+16+8+8 = 52 KB -> 2 blocks/CU; grid 2x16x16 = 512 = full
// residency at 2/CU.
// ---------------------------------------------------------------------------
__global__ __launch_bounds__(256, 2) void fused_main(
    const float* __restrict__ x, const unsigned short* __restrict__ f_bf,
    const unsigned short* __restrict__ Q1, const unsigned short* __restrict__ Q2,
    const float* __restrict__ pws, float* __restrict__ out) {
  const int h = blockIdx.z;
  const int n0 = blockIdx.x * 256;  // p tile
  const int m0 = blockIdx.y * 128;  // b tile
  const int t = threadIdx.x;
  const int wave = t >> 6, lane = t & 63;
  const int wm = wave & 1, wn = wave >> 1;
  const int quad = lane >> 4, lr = lane & 15;
  const int key8 = lr & 7;         // swizzle key for 128B-row buffer (sF)
  const int key2 = (lr >> 1) & 3;  // swizzle key for 64B-row buffers (sQ/sX)

  __shared__ __align__(16) char sF[4096];
  __shared__ __align__(16) char sQ1[16384];
  __shared__ __align__(16) char sQ2[16384];
  __shared__ __align__(16) char sXw[8192];
  __shared__ __align__(16) char sXp[8192];

  // Xh B-operand fragments, loaded fp32 and packed in-register.
  // wave covers b = m0 + wave*32 .. +31 ; k = s*32 + quad*8 + j over d=64
  bf16x8 xh[2][2];
#pragma unroll
  for (int bn = 0; bn < 2; ++bn)
#pragma unroll
    for (int s = 0; s < 2; ++s) {
      int b = m0 + wave * 32 + bn * 16 + lr;
      const float* xr = x + (size_t)b * 1024 + h * 64 + s * 32 + quad * 8;
      fl4 v0 = *(const fl4*)xr;
      fl4 v1 = *(const fl4*)(xr + 4);
      union { unsigned u[4]; bf16x8 v; } cv;
      cv.u[0] = pkbf(v0.x, v0.y);
      cv.u[1] = pkbf(v0.z, v0.w);
      cv.u[2] = pkbf(v1.x, v1.y);
      cv.u[3] = pkbf(v1.z, v1.w);
      xh[bn][s] = cv.v;
    }

  // ---- hoisted (loop-invariant) LDS byte offsets ----
  int af_off[2][2];  // step B reads: sF row fm*16+lr, global chunk s*4+quad
#pragma unroll
  for (int fm = 0; fm < 2; ++fm)
#pragma unroll
    for (int s = 0; s < 2; ++s)
      af_off[fm][s] = (fm * 16 + lr) * 128 + (((s * 4 + quad) ^ key8) * 16);

  int cw_off[2][2];  // step C writes: row wave*32+bn*16+lr, chunk fm*2+(quad>>1)
#pragma unroll
  for (int fm = 0; fm < 2; ++fm)
#pragma unroll
    for (int bn = 0; bn < 2; ++bn)
      cw_off[fm][bn] = (wave * 32 + bn * 16 + lr) * 64 +
                       (((fm * 2 + (quad >> 1)) ^ key2) * 16) + (quad & 1) * 8;

  int aw_off[4];  // step D A reads: row wm*64+fm*16+lr, chunk quad
#pragma unroll
  for (int fm = 0; fm < 4; ++fm)
    aw_off[fm] = (wm * 64 + fm * 16 + lr) * 64 + ((quad ^ key2) * 16);

  int bq_off[8];  // step D B reads: row wn*128+fn*16+lr, chunk quad
#pragma unroll
  for (int fn = 0; fn < 8; ++fn)
    bq_off[fn] = (wn * 128 + fn * 16 + lr) * 64 + ((quad ^ key2) * 16);

  // ---- staging source pointers (swizzle applied on the GLOBAL side) ----
  const char* srcF;
  {
    int row = t >> 3, c = t & 7, cs = c ^ (row & 7);
    srcF = (const char*)f_bf + h * 128 + (size_t)row * 2048 + cs * 16;
  }
  const char* srcQ1[4];
  const char* srcQ2[4];
  {
    const char* q1b = (const char*)(Q1 + ((size_t)h * PP + n0) * FF);
    const char* q2b = (const char*)(Q2 + ((size_t)h * PP + n0) * FF);
#pragma unroll
    for (int r = 0; r < 4; ++r) {
      int ci = r * 256 + t, row = ci >> 2, c = ci & 3, cs = c ^ ((row >> 1) & 3);
      srcQ1[r] = q1b + (size_t)row * 8192 + cs * 16;
      srcQ2[r] = q2b + (size_t)row * 8192 + cs * 16;
    }
  }

  f32x4 acc[4][8];
#pragma unroll
  for (int i = 0; i < 4; ++i)
#pragma unroll
    for (int j = 0; j < 8; ++j) acc[i][j] = (f32x4){0.f, 0.f, 0.f, 0.f};

  for (int it = 0; it < FF / 32; ++it) {
    __syncthreads();  // previous iteration's LDS reads complete
    gload_lds16(srcF, sF + t * 16);
    srcF += 32 * 2048;
#pragma unroll
    for (int r = 0; r < 4; ++r) {
      gload_lds16(srcQ1[r], sQ1 + r * 4096 + t * 16);
      gload_lds16(srcQ2[r], sQ2 + r * 4096 + t * 16);
      srcQ1[r] += 64;
      srcQ2[r] += 64;
    }
    __syncthreads();  // staging visible

    // step B: Xf[f 0..31][b wave*32..+31]
    f32x4 xf[2][2];
#pragma unroll
    for (int fm = 0; fm < 2; ++fm)
#pragma unroll
      for (int bn = 0; bn < 2; ++bn) xf[fm][bn] = (f32x4){0.f, 0.f, 0.f, 0.f};
#pragma unroll
    for (int s = 0; s < 2; ++s)
#pragma unroll
      for (int fm = 0; fm < 2; ++fm) {
        bf16x8 af = *(const bf16x8*)(sF + af_off[fm][s]);
#pragma unroll
        for (int bn = 0; bn < 2; ++bn)
          xf[fm][bn] = __builtin_amdgcn_mfma_f32_16x16x32_bf16(af, xh[bn][s],
                                                               xf[fm][bn], 0, 0, 0);
      }

    // step C: transform + pack (lane holds f = fm*16+quad*4+i, b = wave*32+bn*16+lr)
#pragma unroll
    for (int fm = 0; fm < 2; ++fm)
#pragma unroll
      for (int bn = 0; bn < 2; ++bn) {
        float v0 = xf[fm][bn][0], v1 = xf[fm][bn][1];
        float v2 = xf[fm][bn][2], v3 = xf[fm][bn][3];
        float p0 = fmaxf(v0, 0.f), p1 = fmaxf(v1, 0.f);
        float p2 = fmaxf(v2, 0.f), p3 = fmaxf(v3, 0.f);
        u32x2 w, p;
        w.x = pkbf(v0 * p0, v1 * p1);
        w.y = pkbf(v2 * p2, v3 * p3);
        p.x = pkbf(p0, p1);
        p.y = pkbf(p2, p3);
        *(u32x2*)(sXw + cw_off[fm][bn]) = w;
        *(u32x2*)(sXp + cw_off[fm][bn]) = p;
      }
    __syncthreads();  // Xw/Xp visible

    // step D: acc += Xw.Q1^T + Xp.Q2^T  (K=32)
    bf16x8 aw[4], ap[4];
#pragma unroll
    for (int fm = 0; fm < 4; ++fm) {
      aw[fm] = *(const bf16x8*)(sXw + aw_off[fm]);
      ap[fm] = *(const bf16x8*)(sXp + aw_off[fm]);
    }
#pragma unroll
    for (int fn = 0; fn < 8; ++fn) {
      bf16x8 b1 = *(const bf16x8*)(sQ1 + bq_off[fn]);
      bf16x8 b2 = *(const bf16x8*)(sQ2 + bq_off[fn]);
#pragma unroll
      for (int fm = 0; fm < 4; ++fm) {
        acc[fm][fn] = __builtin_amdgcn_mfma_f32_16x16x32_bf16(aw[fm], b1,
                                                              acc[fm][fn], 0, 0, 0);
        acc[fm][fn] = __builtin_amdgcn_mfma_f32_16x16x32_bf16(ap[fm], b2,
                                                              acc[fm][fn], 0, 0, 0);
      }
    }
  }

  // epilogue: subtract pws, store fp32
#pragma unroll
  for (int fn = 0; fn < 8; ++fn) {
    int p = n0 + wn * 128 + fn * 16 + lr;
    float sub = pws[h * PP + p];
#pragma unroll
    for (int fm = 0; fm < 4; ++fm) {
      int brow = m0 + wm * 64 + fm * 16 + quad * 4;
#pragma unroll
      for (int i = 0; i < 4; ++i) {
        out[(size_t)(brow + i) * (NH * PP) + h * PP + p] = acc[fm][fn][i] - sub;
      }
    }
  }
}

extern "C" void kernel_launch(void* const* d_in, const int* in_sizes, int n_in,
                              void* d_out, int out_size, void* d_ws, size_t ws_size,
                              hipStream_t stream) {
  const float* x = (const float*)d_in[0];
  const float* features = (const float*)d_in[1];
  const float* prototypes = (const float*)d_in[2];
  const float* theta = (const float*)d_in[3];
  const float* alpha = (const float*)d_in[4];
  const float* beta = (const float*)d_in[5];
  float* out = (float*)d_out;

  char* ws = (char*)d_ws;
  size_t off = 0;
  auto carve = [&](size_t bytes) -> char* {
    char* p = ws + off;
    off += (bytes + 255) & ~(size_t)255;
    return p;
  };
  unsigned short* f_bf = (unsigned short*)carve((size_t)FF * 1024 * 2);
  unsigned short* p_bf = (unsigned short*)carve((size_t)PP * 1024 * 2);
  unsigned short* Q1 = (unsigned short*)carve((size_t)NH * PP * FF * 2);
  unsigned short* Q2 = (unsigned short*)carve((size_t)NH * PP * FF * 2);
  float* pws = (float*)carve((size_t)NH * PP * 4);

  const int ncvt = (FF + PP) * 1024 / 4;
  cvt_fp<<<(ncvt + 255) / 256, 256, 0, stream>>>(features, prototypes, f_bf, p_bf);
  hipMemsetAsync(pws, 0, (size_t)NH * PP * 4, stream);

  // Phase 1: prototypes -> Q1, Q2, pws
  gemm_proto<<<dim3(FF / 128, PP / 128, NH), 256, 0, stream>>>(
      p_bf, f_bf, Q1, Q2, pws, theta, alpha, beta);

  // Fused main GEMM
  fused_main<<<dim3(PP / 256, BB / 128, NH), 256, 0, stream>>>(
      x, f_bf, Q1, Q2, pws, out);
}